// Round 6
// baseline (3418.095 us; speedup 1.0000x reference)
//
#include <hip/hip_runtime.h>

#define B_ 64
#define S_ 128
#define H_ 512
#define NGRU 256   // GRU-role blocks: 4 batch-tiles x 64 i-groups (8 h-idx each)

// ---------------------------------------------------------------------------
// One kernel per time step t = 0..128 (129 sequential graph nodes).
//   blocks [0, NGRU):    GRU step t -> h(t+1) into hbuf slot (t+1)&1  (t<128)
//     block g: batch tile btile = g>>6 (16 batches), i-group i0 = (g&63)*8.
//     Fuses x-side (emb[dec] @ W_ih^T) and h-side (h @ W_hh^T) matvecs.
//   blocks [NGRU, +64):  attention for output step tt = t-1 using h(t) (t>0)
// All inputs fp32, dec int32, OUTPUT fp32 (round-5 finding: harness expects
// the reference's fp32 dtype; bf16 packing was the rounds-3/4/5 failure).
// Workspace: hbuf only (2 x 64 x 512 f32 = 256 KB).
// ---------------------------------------------------------------------------
__global__ __launch_bounds__(256) void step_kernel(
    const int t,
    const int*   __restrict__ dec,
    const float* __restrict__ eh,     // encoder_hidden [64][512]
    const float* __restrict__ enc,    // encoder_output [64][128][512]
    const float* __restrict__ emb,    // [32000][512]
    const float* __restrict__ wih,    // [1536][512]
    const float* __restrict__ whh,    // [1536][512]
    const float* __restrict__ bih,    // [1536]
    const float* __restrict__ bhh,    // [1536]
    float* __restrict__ hbuf,         // [2][64][512] f32
    float* __restrict__ out)          // [64][128][1024] f32
{
  __shared__ __align__(16) float smem[2 * 16 * 520];   // 66,560 B
  const int tid = threadIdx.x;

  if (blockIdx.x < NGRU) {
    // ---------------- GRU role ----------------
    if (t >= S_) return;
    float* xs = smem;              // [16][520]: x tile
    float* hs = smem + 16 * 520;   // [16][520]: h tile
    const int g = blockIdx.x;
    const int btile = g >> 6;          // 0..3
    const int i0 = (g & 63) * 8;       // h-index group base

    // --- stage x[b][:] = emb[dec[b][t]][:] and h[b][:] into LDS ---
    {
      const int r = tid >> 4, c = tid & 15;     // row 0..15, 32-elem chunk
      const int b = btile * 16 + r;
      const int tok = dec[b * S_ + t];
      const float* src = emb + (size_t)tok * H_ + c * 32;
      float4* dst = (float4*)(xs + r * 520 + c * 32);
      #pragma unroll
      for (int m = 0; m < 8; ++m) dst[m] = ((const float4*)src)[m];
      const float* hsrc = (t == 0)
          ? (eh + b * H_ + c * 32)
          : (hbuf + (size_t)(t & 1) * (B_ * H_) + b * H_ + c * 32);
      float4* hdst = (float4*)(hs + r * 520 + c * 32);
      #pragma unroll
      for (int m = 0; m < 8; ++m) hdst[m] = ((const float4*)hsrc)[m];
    }
    __syncthreads();

    // --- matvecs: thread (b4, q, il): gates (r,z,n) for (b, i=i0+il), k-half q
    const int b4 = tid & 15;
    const int q  = (tid >> 4) & 1;
    const int il = tid >> 5;           // 0..7
    const int i  = i0 + il;
    const int k0 = q * 256;

    const float* xrow = xs + b4 * 520 + k0;
    const float* hrow = hs + b4 * 520 + k0;
    const float* wr_i = wih + (size_t)(i)        * H_ + k0;
    const float* wz_i = wih + (size_t)(512 + i)  * H_ + k0;
    const float* wn_i = wih + (size_t)(1024 + i) * H_ + k0;
    const float* wr_h = whh + (size_t)(i)        * H_ + k0;
    const float* wz_h = whh + (size_t)(512 + i)  * H_ + k0;
    const float* wn_h = whh + (size_t)(1024 + i) * H_ + k0;

    float axr = 0.f, axz = 0.f, axn = 0.f;
    float ahr = 0.f, ahz = 0.f, ahn = 0.f;

    #pragma unroll 2
    for (int c16 = 0; c16 < 16; ++c16) {
      const int off = c16 * 16;
      float4 xv[4], hv[4], wv[4];
      #pragma unroll
      for (int m = 0; m < 4; ++m) {
        xv[m] = ((const float4*)(xrow + off))[m];
        hv[m] = ((const float4*)(hrow + off))[m];
      }
      #define DOT16(ACC, WP, VV)                                   \
        _Pragma("unroll")                                          \
        for (int m = 0; m < 4; ++m) wv[m] = ((const float4*)((WP) + off))[m]; \
        _Pragma("unroll")                                          \
        for (int m = 0; m < 4; ++m) {                              \
          ACC = fmaf(VV[m].x, wv[m].x, ACC);                       \
          ACC = fmaf(VV[m].y, wv[m].y, ACC);                       \
          ACC = fmaf(VV[m].z, wv[m].z, ACC);                       \
          ACC = fmaf(VV[m].w, wv[m].w, ACC);                       \
        }
      DOT16(axr, wr_i, xv)
      DOT16(axz, wz_i, xv)
      DOT16(axn, wn_i, xv)
      DOT16(ahr, wr_h, hv)
      DOT16(ahz, wz_h, hv)
      DOT16(ahn, wn_h, hv)
      #undef DOT16
    }

    // combine k-halves (partner lane differs in bit 4 -> same wave)
    axr += __shfl_xor(axr, 16);
    axz += __shfl_xor(axz, 16);
    axn += __shfl_xor(axn, 16);
    ahr += __shfl_xor(ahr, 16);
    ahz += __shfl_xor(ahz, 16);
    ahn += __shfl_xor(ahn, 16);

    if (q == 0) {
      const float ir  = axr + bih[i];
      const float iz  = axz + bih[512 + i];
      const float in2 = axn + bih[1024 + i];
      const float hr  = ahr + bhh[i];
      const float hz  = ahz + bhh[512 + i];
      const float hn  = ahn + bhh[1024 + i];
      const float rr = 1.f / (1.f + expf(-(ir + hr)));
      const float zz = 1.f / (1.f + expf(-(iz + hz)));
      const float nn = tanhf(in2 + rr * hn);
      const int b = btile * 16 + b4;
      const float hold = (t == 0) ? eh[b * H_ + i]
                                  : hbuf[(size_t)(t & 1) * (B_ * H_) + b * H_ + i];
      hbuf[(size_t)((t + 1) & 1) * (B_ * H_) + b * H_ + i] =
          (1.f - zz) * nn + zz * hold;
    }
  } else {
    // ---------------- attention role (output step tt = t-1) ----------------
    if (t == 0) return;
    const int b = blockIdx.x - NGRU;
    const int tt = t - 1;
    float* hsm = smem;              // 512 f32: h(t)[b]
    float* pp  = hsm + 512;         // 128 f32: scores -> probs
    float* red = pp + 128;          // 4 f32: cross-wave reduce
    const float* hsrc = hbuf + (size_t)(t & 1) * (B_ * H_) + b * H_;
    *(float2*)(hsm + tid * 2) = *(const float2*)(hsrc + tid * 2);
    __syncthreads();

    // scores[s] = h . enc[b][s][:]  (2 threads per s, k-halves)
    const int s = tid >> 1, hf2 = tid & 1;
    float sc = 0.f;
    {
      const float* erow = enc + ((size_t)b * S_ + s) * H_ + hf2 * 256;
      const float* hp = hsm + hf2 * 256;
      #pragma unroll 8
      for (int c = 0; c < 64; ++c) {
        const float4 ev = ((const float4*)erow)[c];
        const float4 hv = ((const float4*)hp)[c];
        sc = fmaf(ev.x, hv.x, sc);
        sc = fmaf(ev.y, hv.y, sc);
        sc = fmaf(ev.z, hv.z, sc);
        sc = fmaf(ev.w, hv.w, sc);
      }
    }
    sc += __shfl_xor(sc, 1);
    if (hf2 == 0) pp[s] = sc;
    __syncthreads();

    float e = 0.f, v = 0.f;
    if (tid < 128) {
      v = pp[tid];
      float m = v;
      #pragma unroll
      for (int o = 32; o > 0; o >>= 1) m = fmaxf(m, __shfl_xor(m, o));
      if ((tid & 63) == 0) red[tid >> 6] = m;
    }
    __syncthreads();
    const float mx = fmaxf(red[0], red[1]);
    if (tid < 128) {
      e = expf(v - mx);
      float s2 = e;
      #pragma unroll
      for (int o = 32; o > 0; o >>= 1) s2 += __shfl_xor(s2, o);
      if ((tid & 63) == 0) red[2 + (tid >> 6)] = s2;
    }
    __syncthreads();
    const float inv = 1.f / (red[2] + red[3]);
    if (tid < 128) pp[tid] = e * inv;
    __syncthreads();

    // context[i] = sum_s p[s] * enc[b][s][i]   (2 i's per thread, coalesced)
    const int i2 = tid * 2;
    float c0 = 0.f, c1 = 0.f;
    const float* ecol = enc + (size_t)b * (S_ * H_) + i2;
    for (int s2 = 0; s2 < 128; ++s2) {
      const float2 u = *(const float2*)(ecol + (size_t)s2 * H_);
      const float p = pp[s2];
      c0 = fmaf(p, u.x, c0);
      c1 = fmaf(p, u.y, c1);
    }
    // fp32 output: out[b][tt][0:512] = h(t), out[b][tt][512:1024] = context
    const size_t base = ((size_t)b * S_ + tt) * (2 * H_);
    const float2 hv = *(const float2*)(hsm + i2);
    *(float2*)(out + base + i2)       = hv;
    *(float2*)(out + base + 512 + i2) = make_float2(c0, c1);
  }
}

// ---------------------------------------------------------------------------
extern "C" void kernel_launch(void* const* d_in, const int* in_sizes, int n_in,
                              void* d_out, int out_size, void* d_ws, size_t ws_size,
                              hipStream_t stream) {
  (void)in_sizes; (void)n_in; (void)out_size; (void)ws_size;
  const int*   dec = (const int*)d_in[0];
  const float* eh  = (const float*)d_in[1];
  const float* enc = (const float*)d_in[2];
  const float* emb = (const float*)d_in[3];
  const float* wih = (const float*)d_in[4];
  const float* whh = (const float*)d_in[5];
  const float* bih = (const float*)d_in[6];
  const float* bhh = (const float*)d_in[7];
  float* out = (float*)d_out;

  float* hbuf = (float*)d_ws;   // [2][64][512] f32 = 256 KB — only workspace use

  for (int t = 0; t <= S_; ++t)
    step_kernel<<<NGRU + B_, 256, 0, stream>>>(t, dec, eh, enc, emb, wih, whh,
                                               bih, bhh, hbuf, out);
}